// Round 3
// baseline (420.667 us; speedup 1.0000x reference)
//
#include <hip/hip_runtime.h>
#include <math.h>

#define H 160
#define W 480
#define HW 76800
#define NPTS 120000

// ws layout (bytes):
//   winner0 @ 0        (76800*4)         dead after compact; sa aliases
//   winner1 @ 307200
//   winner2 @ 614400
//   cnt     @ 921600   3 ints (+pad)
//   t9img   @ 921616   2 halves x 9 x HW floats = 5,529,600
//   t9v0    @ 6451216  HW x 12 floats (AoS, 48B/cell) = 3,686,400
//   t9v1    @ 10137616
//   t9v2    @ 13824016
//   list0   @ 17510416 HW x int2 = 614,400
//   list1   @ 18124816
//   list2   @ 18739216
//   Weff0   @ 19353616 (64*12*4)
//   Weff1   @ 19356688 (128*12*4)
//   bconst  @ 19362832 (9*4)
#define OFF_W1M   307200
#define OFF_W2M   614400
#define OFF_CNT   921600
#define OFF_T9I   921616
#define OFF_T9V0  6451216
#define OFF_T9V1  10137616
#define OFF_T9V2  13824016
#define OFF_L0    17510416
#define OFF_L1    18124816
#define OFF_L2    18739216
#define OFF_WE0   19353616
#define OFF_WE1   19356688
#define OFF_BC    19362832

// blocks [0,7): weight folding + counter zeroing; blocks [7,...): winner scatter
__global__ __launch_bounds__(256) void prep_and_scatter(
    const float* __restrict__ rw0, const float* __restrict__ rw1,
    const float* __restrict__ rb0, const float* __restrict__ rb1,
    const float* __restrict__ sbw,
    float* __restrict__ Weff0, float* __restrict__ Weff1, float* __restrict__ bconst,
    int* __restrict__ cnt,
    const int2* __restrict__ g0, const int2* __restrict__ g1, const int2* __restrict__ g2,
    int* __restrict__ w0, int* __restrict__ w1, int* __restrict__ w2) {
  if (blockIdx.x < 7) {
    int t = blockIdx.x * 256 + threadIdx.x;
    if (t < 576) {
      int jj = t / 64, k = t % 64;
      float s = 0.f;
      for (int c = 0; c < 256; ++c) s = fmaf(rw0[c * 64 + k], sbw[(256 + c) * 9 + jj], s);
      Weff0[k * 12 + jj] = s;
    } else if (t < 1728) {
      int tt = t - 576;
      int jj = tt / 128, k = tt % 128;
      float s = 0.f;
      for (int c = 0; c < 256; ++c) s = fmaf(rw1[c * 128 + k], sbw[(256 + c) * 9 + jj], s);
      Weff1[k * 12 + jj] = s;
    } else if (t < 1737) {
      int jj = t - 1728;
      float s = 0.f;
      for (int c = 0; c < 256; ++c) s = fmaf(rb0[c] + rb1[c], sbw[(256 + c) * 9 + jj], s);
      bconst[jj] = s;
    } else if (t < 1740) {
      cnt[t - 1737] = 0;
    }
  } else {
    int j = (blockIdx.x - 7) * 256 + threadIdx.x;
    if (j >= NPTS) return;
    int2 c;
    c = g0[j];
    if ((unsigned)c.x < W && (unsigned)c.y < H) atomicMax(&w0[c.y * W + c.x], j);
    c = g1[j];
    if ((unsigned)c.x < W && (unsigned)c.y < H) atomicMax(&w1[c.y * W + c.x], j);
    c = g2[j];
    if ((unsigned)c.x < W && (unsigned)c.y < H) atomicMax(&w2[c.y * W + c.x], j);
  }
}

// winners -> per-level (j, cell) lists via ballot compaction (1 atomic / wave / level)
__global__ __launch_bounds__(256) void compact_kernel(
    const int* __restrict__ w0m, const int* __restrict__ w1m, const int* __restrict__ w2m,
    int2* __restrict__ L0o, int2* __restrict__ L1o, int2* __restrict__ L2o,
    int* __restrict__ cnt) {
  int p = blockIdx.x * 256 + threadIdx.x;  // exact HW, all lanes active
  int lane = threadIdx.x & 63;
#pragma unroll
  for (int l = 0; l < 3; ++l) {
    int w = (l == 0) ? w0m[p] : (l == 1) ? w1m[p] : w2m[p];
    int2* Lo = (l == 0) ? L0o : (l == 1) ? L1o : L2o;
    unsigned long long m = __ballot(w >= 0);
    int c = __popcll(m);
    int base = 0;
    if (lane == 0 && c) base = atomicAdd(&cnt[l], c);
    base = __shfl(base, 0);
    if (w >= 0) {
      int off = __popcll(m & ((1ull << lane) - 1ull));
      Lo[base + off] = make_int2(w, p);
    }
  }
}

// Point-centric voxel pass. Block = 64 winning points.
//  - stage: rows -> LDS transposed [c][pt], stride 65 (odd): global b32 loads are
//    fully coalesced (256B/instr), LDS writes conflict-free (bank = (c + r) % 32).
//  - compute: pt = t&63, q = t>>6 (wave-uniform -> weights via s_load);
//    ldsT reads have lane=pt -> consecutive banks, conflict-free.
//  - reduce: 4 q-partials via padded LDS array; one 48B AoS record per point.
template <int CH>
__device__ __forceinline__ void vox_body(
    const int2* __restrict__ list, int n, const float* __restrict__ vf,
    const float* __restrict__ wbase, int wstride, float* __restrict__ out,
    float* ldsT, float* part, int2* ent) {
  const int CPQ = CH / 4;
  int t = threadIdx.x;
  int i0 = blockIdx.x * 64;
  if (i0 >= n) return;
  if (t < 64) {
    int idx = i0 + t;
    ent[t] = (idx < n) ? list[idx] : make_int2(0, -1);  // sentinel: stage row 0, skip write
  }
  __syncthreads();
#pragma unroll
  for (int k = 0; k < CPQ; ++k) {
    int flat = t + 256 * k;
    int r = flat / CH;   // wave-uniform row index
    int c = flat % CH;
    ldsT[c * 65 + r] = vf[(size_t)ent[r].x * CH + c];
  }
  __syncthreads();
  int pt = t & 63;
  int q = __builtin_amdgcn_readfirstlane(t >> 6);
  int c0 = q * CPQ;
  float acc[9];
#pragma unroll
  for (int j = 0; j < 9; ++j) acc[j] = 0.f;
#pragma unroll 8
  for (int i = 0; i < CPQ; ++i) {
    float v = ldsT[(c0 + i) * 65 + pt];
    const float* wr = wbase + (c0 + i) * wstride;  // wave-uniform -> s_load
#pragma unroll
    for (int j = 0; j < 9; ++j) acc[j] = fmaf(v, wr[j], acc[j]);
  }
#pragma unroll
  for (int j = 0; j < 9; ++j) part[pt * 37 + j * 4 + q] = acc[j];
  __syncthreads();
  if (t < 64) {
    int2 e = ent[t];
    if (e.y >= 0) {
      float s[9];
#pragma unroll
      for (int j = 0; j < 9; ++j)
        s[j] = (part[t * 37 + j * 4 + 0] + part[t * 37 + j * 4 + 1]) +
               (part[t * 37 + j * 4 + 2] + part[t * 37 + j * 4 + 3]);
      float* d = out + (size_t)e.y * 12;
      *(float4*)(d + 0) = make_float4(s[0], s[1], s[2], s[3]);
      *(float4*)(d + 4) = make_float4(s[4], s[5], s[6], s[7]);
      d[8] = s[8];
    }
  }
}

__global__ __launch_bounds__(256) void vox_kernel(
    const int2* __restrict__ l0, const int2* __restrict__ l1, const int2* __restrict__ l2,
    const int* __restrict__ cnt,
    const float* __restrict__ vf0, const float* __restrict__ vf1,
    const float* __restrict__ vf2,
    const float* __restrict__ We0, const float* __restrict__ We1,
    const float* __restrict__ sbw,
    float* __restrict__ t9v0, float* __restrict__ t9v1, float* __restrict__ t9v2) {
  __shared__ float ldsT[256 * 65];   // 66,560 B
  __shared__ float part[64 * 37];    //  9,472 B
  __shared__ int2 ent[64];           //    512 B
  int z = blockIdx.y;
  if (z == 2)      vox_body<256>(l2, cnt[2], vf2, sbw + 256 * 9, 9, t9v2, ldsT, part, ent);
  else if (z == 1) vox_body<128>(l1, cnt[1], vf1, We1, 12, t9v1, ldsT, part, ent);
  else             vox_body<64> (l0, cnt[0], vf0, We0, 12, t9v0, ldsT, part, ent);
}

// img part: thread/pixel, 128 channels per blockIdx.y half, planar output.
__global__ __launch_bounds__(256) void img_kernel(
    const float* __restrict__ img, const float* __restrict__ seg,
    const float* __restrict__ sbw, float* __restrict__ t9i) {
  int p = blockIdx.x * 256 + threadIdx.x;  // exact HW
  int hh = blockIdx.y;
  int c0 = hh * 128;
  float acc[9];
#pragma unroll
  for (int j = 0; j < 9; ++j) acc[j] = 0.f;
  for (int cc = 0; cc < 128; cc += 16) {
    float v[16];
#pragma unroll
    for (int tt = 0; tt < 16; ++tt) v[tt] = img[(size_t)(c0 + cc + tt) * HW + p];
#pragma unroll
    for (int tt = 0; tt < 16; ++tt) {
      const float* wr = sbw + (c0 + cc + tt) * 9;  // wave-uniform -> s_load
#pragma unroll
      for (int j = 0; j < 9; ++j) acc[j] = fmaf(v[tt], wr[j], acc[j]);
    }
  }
  float s = seg[HW + p];
  float* dst = t9i + (size_t)hh * 9 * HW + p;
#pragma unroll
  for (int j = 0; j < 9; ++j) dst[(size_t)j * HW] = acc[j] * s;
}

// attention = sigmoid(sbb + sum over valid taps (bconst[j] + img-planar + 3x vox-AoS))
__global__ __launch_bounds__(256) void conv_sig_kernel(
    const float* __restrict__ t9i, const float* __restrict__ t9v0,
    const float* __restrict__ t9v1, const float* __restrict__ t9v2,
    const float* __restrict__ bconst, const float* __restrict__ sbb,
    const float* __restrict__ seg, float* __restrict__ sa) {
  int p = blockIdx.x * blockDim.x + threadIdx.x;  // exact HW
  int y = p / W, x = p - y * W;
  float s = sbb[0];
#pragma unroll
  for (int dy = -1; dy <= 1; ++dy) {
#pragma unroll
    for (int dx = -1; dx <= 1; ++dx) {
      int yy = y + dy, xx = x + dx;
      if ((unsigned)yy < H && (unsigned)xx < W) {
        int j = (dy + 1) * 3 + (dx + 1);
        int q = yy * W + xx;
        float t = bconst[j] + t9i[(size_t)j * HW + q] + t9i[(size_t)(9 + j) * HW + q];
        t += t9v0[(size_t)q * 12 + j] + t9v1[(size_t)q * 12 + j] + t9v2[(size_t)q * 12 + j];
        s += t;
      }
    }
  }
  float att = 1.f / (1.f + expf(-s));
  sa[p] = att * seg[HW + p];
}

// out[c][p] = img[c][p] * sa[p]
__global__ __launch_bounds__(256) void final_mul_kernel(
    const float* __restrict__ img, const float* __restrict__ sa, float* __restrict__ out) {
  int i = blockIdx.x * blockDim.x + threadIdx.x;  // float4 index, exact 4915200
  int e = i * 4;
  int p = e % HW;  // 76800 % 4 == 0 so float4 stays within one channel row
  float4 v = *(const float4*)(img + e);
  float4 g = *(const float4*)(sa + p);
  float4 o = make_float4(v.x * g.x, v.y * g.y, v.z * g.z, v.w * g.w);
  *(float4*)(out + e) = o;
}

extern "C" void kernel_launch(void* const* d_in, const int* in_sizes, int n_in,
                              void* d_out, int out_size, void* d_ws, size_t ws_size,
                              hipStream_t stream) {
  const float* img = (const float*)d_in[0];
  const float* seg = (const float*)d_in[1];
  int iV0 = 2, iG0 = 3, iV1 = 4, iG1 = 5, iV2 = 6, iG2 = 7;
  if (in_sizes[3] != 2 * NPTS) {  // grouped (reference-arg) order fallback
    iV0 = 2; iV1 = 3; iV2 = 4; iG0 = 5; iG1 = 6; iG2 = 7;
  }
  const float* vf0 = (const float*)d_in[iV0];
  const float* vf1 = (const float*)d_in[iV1];
  const float* vf2 = (const float*)d_in[iV2];
  const int2* g0 = (const int2*)d_in[iG0];
  const int2* g1 = (const int2*)d_in[iG1];
  const int2* g2 = (const int2*)d_in[iG2];
  const float* rw0 = (const float*)d_in[8];
  const float* rb0 = (const float*)d_in[9];
  const float* rw1 = (const float*)d_in[10];
  const float* rb1 = (const float*)d_in[11];
  const float* sbw = (const float*)d_in[12];
  const float* sbb = (const float*)d_in[13];

  char* ws = (char*)d_ws;
  int* w0m = (int*)(ws + 0);
  int* w1m = (int*)(ws + OFF_W1M);
  int* w2m = (int*)(ws + OFF_W2M);
  int* cnt = (int*)(ws + OFF_CNT);
  float* t9i = (float*)(ws + OFF_T9I);
  float* t9v0 = (float*)(ws + OFF_T9V0);
  float* t9v1 = (float*)(ws + OFF_T9V1);
  float* t9v2 = (float*)(ws + OFF_T9V2);
  int2* l0 = (int2*)(ws + OFF_L0);
  int2* l1 = (int2*)(ws + OFF_L1);
  int2* l2 = (int2*)(ws + OFF_L2);
  float* Weff0 = (float*)(ws + OFF_WE0);
  float* Weff1 = (float*)(ws + OFF_WE1);
  float* bconst = (float*)(ws + OFF_BC);
  float* sa = (float*)(ws + 0);  // aliases winner maps (dead after compact)

  float* out = (float*)d_out;

  hipMemsetAsync(w0m, 0xFF, 3 * 307200, stream);           // winners = -1
  hipMemsetAsync(ws + OFF_T9V0, 0, 3 * 3686400, stream);   // vox AoS buffers = 0
  prep_and_scatter<<<7 + (NPTS + 255) / 256, 256, 0, stream>>>(
      rw0, rw1, rb0, rb1, sbw, Weff0, Weff1, bconst, cnt, g0, g1, g2, w0m, w1m, w2m);
  compact_kernel<<<HW / 256, 256, 0, stream>>>(w0m, w1m, w2m, l0, l1, l2, cnt);
  dim3 vg(HW / 64, 3);  // 1200 blocks/level max; excess blocks exit on count
  vox_kernel<<<vg, 256, 0, stream>>>(l0, l1, l2, cnt, vf0, vf1, vf2,
                                     Weff0, Weff1, sbw, t9v0, t9v1, t9v2);
  dim3 ig(HW / 256, 2);
  img_kernel<<<ig, 256, 0, stream>>>(img, seg, sbw, t9i);
  conv_sig_kernel<<<HW / 256, 256, 0, stream>>>(t9i, t9v0, t9v1, t9v2,
                                                bconst, sbb, seg, sa);
  final_mul_kernel<<<(out_size / 4) / 256, 256, 0, stream>>>(img, sa, out);
}

// Round 4
// 368.148 us; speedup vs baseline: 1.1427x; 1.1427x over previous
//
#include <hip/hip_runtime.h>
#include <math.h>

#define H 160
#define W 480
#define HW 76800
#define NPTS 120000
#define NUNIT 6

// ws layout (bytes):
//   winner0 @ 0        (76800*4)
//   winner1 @ 307200
//   winner2 @ 614400
//   t9      @ 921600   planar: 6 units x 9 taps x [HW] floats = 16,588,800 B
//   Weff0   @ 17510400 (64*12*4  = 3072)   layout [c][12]
//   Weff1   @ 17513472 (128*12*4 = 6144)   layout [c][12]
//   bconst  @ 17519616 (9*4)
//   sa      @ 0        (aliases winner0; winners dead after t9_kernel)
#define OFF_W1M 307200
#define OFF_W2M 614400
#define OFF_T9  921600
#define OFF_WE0 17510400
#define OFF_WE1 17513472
#define OFF_BC  17519616

// blocks [0,7): weight folding; blocks [7,...): winner scatter
__global__ __launch_bounds__(256) void prep_and_scatter(
    const float* __restrict__ rw0, const float* __restrict__ rw1,
    const float* __restrict__ rb0, const float* __restrict__ rb1,
    const float* __restrict__ sbw,
    float* __restrict__ Weff0, float* __restrict__ Weff1, float* __restrict__ bconst,
    const int2* __restrict__ g0, const int2* __restrict__ g1, const int2* __restrict__ g2,
    int* __restrict__ w0, int* __restrict__ w1, int* __restrict__ w2) {
  if (blockIdx.x < 7) {
    int t = blockIdx.x * 256 + threadIdx.x;
    if (t < 576) {
      int jj = t / 64, k = t % 64;
      float s = 0.f;
      for (int c = 0; c < 256; ++c) s = fmaf(rw0[c * 64 + k], sbw[(256 + c) * 9 + jj], s);
      Weff0[k * 12 + jj] = s;
    } else if (t < 1728) {
      int tt = t - 576;
      int jj = tt / 128, k = tt % 128;
      float s = 0.f;
      for (int c = 0; c < 256; ++c) s = fmaf(rw1[c * 128 + k], sbw[(256 + c) * 9 + jj], s);
      Weff1[k * 12 + jj] = s;
    } else if (t < 1737) {
      int jj = t - 1728;
      float s = 0.f;
      for (int c = 0; c < 256; ++c) s = fmaf(rb0[c] + rb1[c], sbw[(256 + c) * 9 + jj], s);
      bconst[jj] = s;
    }
  } else {
    int j = (blockIdx.x - 7) * 256 + threadIdx.x;
    if (j >= NPTS) return;
    int2 c;
    c = g0[j];
    if ((unsigned)c.x < W && (unsigned)c.y < H) atomicMax(&w0[c.y * W + c.x], j);
    c = g1[j];
    if ((unsigned)c.x < W && (unsigned)c.y < H) atomicMax(&w1[c.y * W + c.x], j);
    c = g2[j];
    if ((unsigned)c.x < W && (unsigned)c.y < H) atomicMax(&w2[c.y * W + c.x], j);
  }
}

// Async gather: per-lane global float4 -> linear LDS (base + lane*16), no VGPR
// round-trip, vmcnt-counted. The in-flight depth fix rounds 1/2 couldn't get
// through the register allocator.
__device__ __forceinline__ void glds16(const float* g, float* l) {
  __builtin_amdgcn_global_load_lds(
      (const __attribute__((address_space(1))) void*)g,
      (__attribute__((address_space(3))) void*)l, 16, 0, 0);
}

// One staged segment: NG f4-chunks (NG<=8). Issue NG async gathers (8 KB in
// flight per wave at NG=8), wait own vmcnt, then FMA from LDS. LDS read is
// lane-stride 16B -> 2-way bank alias (free, m136). Weights wave-uniform.
template <int NG, int WS>
__device__ __forceinline__ void seg_lds(const float4* row, const float* __restrict__ wbase,
                                        bool act, int lane, float* buf, float acc[9]) {
#pragma unroll
  for (int k = 0; k < NG; ++k) glds16((const float*)(row + k), buf + k * 256);
  asm volatile("s_waitcnt vmcnt(0)" ::: "memory");
  __builtin_amdgcn_sched_barrier(0);
  if (act) {
#pragma unroll
    for (int k = 0; k < NG; ++k) {
      float4 v = *(const float4*)(buf + k * 256 + lane * 4);
      const float* wc = wbase + 4 * k * WS;
#pragma unroll
      for (int j = 0; j < 9; ++j) {
        acc[j] = fmaf(v.x, wc[j], acc[j]);
        acc[j] = fmaf(v.y, wc[WS + j], acc[j]);
        acc[j] = fmaf(v.z, wc[2 * WS + j], acc[j]);
        acc[j] = fmaf(v.w, wc[3 * WS + j], acc[j]);
      }
    }
  }
}

// Thread-per-pixel, uniform work unit per blockIdx.y (6 units, balanced):
//   unit 0: img c[0,128)   * seg      (coalesced stream)
//   unit 1: img c[128,256) * seg      (coalesced stream)
//   unit 2: vox L0 all 64   + L1 c[0,48)      (16+12 = 28 f4 gathers)
//   unit 3: vox L1 c[48,128)+ L2 c[0,32)      (20+8  = 28 f4 gathers)
//   unit 4: vox L2 c[32,144)                  (28 f4 gathers)
//   unit 5: vox L2 c[144,256)                 (28 f4 gathers)
// Empty cells stage row 0 (L2-hot, branch-free issue); FMAs lane-guarded.
__global__ __launch_bounds__(256) void t9_kernel(
    const float* __restrict__ img, const float* __restrict__ seg,
    const float* __restrict__ vf0, const float* __restrict__ vf1,
    const float* __restrict__ vf2,
    const int* __restrict__ w0m, const int* __restrict__ w1m,
    const int* __restrict__ w2m,
    const float* __restrict__ We0, const float* __restrict__ We1,
    const float* __restrict__ sbw, float* __restrict__ t9) {
  __shared__ float stg[4][2048];  // 8 KB per wave, 32 KB per block
  int p = blockIdx.x * 256 + threadIdx.x;  // exact 76800
  int u = blockIdx.y;
  int lane = threadIdx.x & 63;
  float* buf = stg[threadIdx.x >> 6];
  float acc[9];
#pragma unroll
  for (int j = 0; j < 9; ++j) acc[j] = 0.f;

  if (u < 2) {
    const int c0 = u * 128;
    float s = seg[HW + p];
    for (int cc = 0; cc < 128; cc += 16) {
      float v[16];
#pragma unroll
      for (int t = 0; t < 16; ++t) v[t] = img[(size_t)(c0 + cc + t) * HW + p];
      __builtin_amdgcn_sched_barrier(0);
#pragma unroll
      for (int t = 0; t < 16; ++t) {
        const float* wr = sbw + (c0 + cc + t) * 9;
#pragma unroll
        for (int j = 0; j < 9; ++j) acc[j] = fmaf(v[t], wr[j], acc[j]);
      }
    }
#pragma unroll
    for (int j = 0; j < 9; ++j) acc[j] *= s;
  } else if (u == 2) {
    int w0 = w0m[p], w1 = w1m[p];
    const float4* r0 = (const float4*)(vf0 + (size_t)(w0 < 0 ? 0 : w0) * 64);
    const float4* r1 = (const float4*)(vf1 + (size_t)(w1 < 0 ? 0 : w1) * 128);
    seg_lds<8, 12>(r0, We0, w0 >= 0, lane, buf, acc);
    seg_lds<8, 12>(r0 + 8, We0 + 32 * 12, w0 >= 0, lane, buf, acc);
    seg_lds<8, 12>(r1, We1, w1 >= 0, lane, buf, acc);
    seg_lds<4, 12>(r1 + 8, We1 + 32 * 12, w1 >= 0, lane, buf, acc);
  } else if (u == 3) {
    int w1 = w1m[p], w2 = w2m[p];
    const float4* r1 = (const float4*)(vf1 + (size_t)(w1 < 0 ? 0 : w1) * 128 + 48);
    const float4* r2 = (const float4*)(vf2 + (size_t)(w2 < 0 ? 0 : w2) * 256);
    seg_lds<8, 12>(r1, We1 + 48 * 12, w1 >= 0, lane, buf, acc);
    seg_lds<8, 12>(r1 + 8, We1 + 80 * 12, w1 >= 0, lane, buf, acc);
    seg_lds<4, 12>(r1 + 16, We1 + 112 * 12, w1 >= 0, lane, buf, acc);
    seg_lds<8, 9>(r2, sbw + 256 * 9, w2 >= 0, lane, buf, acc);
  } else {
    int cbase = (u == 4) ? 32 : 144;
    int w2 = w2m[p];
    const float4* r2 = (const float4*)(vf2 + (size_t)(w2 < 0 ? 0 : w2) * 256 + cbase);
    const float* wb = sbw + (256 + cbase) * 9;
    bool act = (w2 >= 0);
    seg_lds<8, 9>(r2, wb, act, lane, buf, acc);
    seg_lds<8, 9>(r2 + 8, wb + 32 * 9, act, lane, buf, acc);
    seg_lds<8, 9>(r2 + 16, wb + 64 * 9, act, lane, buf, acc);
    seg_lds<4, 9>(r2 + 24, wb + 96 * 9, act, lane, buf, acc);
  }

  float* dst = t9 + (size_t)u * 9 * HW + p;
#pragma unroll
  for (int j = 0; j < 9; ++j) dst[(size_t)j * HW] = acc[j];  // 9 coalesced stores
}

// attention = sigmoid(sb_b + sum over valid taps (bconst[j] + sum_units t9[u][j][q]))
__global__ __launch_bounds__(256) void conv_sig_kernel(
    const float* __restrict__ t9, const float* __restrict__ bconst,
    const float* __restrict__ sbb, const float* __restrict__ seg,
    float* __restrict__ sa) {
  int p = blockIdx.x * blockDim.x + threadIdx.x;  // exact 76800
  int y = p / W, x = p - y * W;
  float s = sbb[0];
#pragma unroll
  for (int dy = -1; dy <= 1; ++dy) {
#pragma unroll
    for (int dx = -1; dx <= 1; ++dx) {
      int yy = y + dy, xx = x + dx;
      if ((unsigned)yy < H && (unsigned)xx < W) {
        int j = (dy + 1) * 3 + (dx + 1);
        int q = yy * W + xx;
        float t = bconst[j];
#pragma unroll
        for (int u = 0; u < NUNIT; ++u) t += t9[(size_t)(u * 9 + j) * HW + q];
        s += t;
      }
    }
  }
  float att = 1.f / (1.f + expf(-s));
  sa[p] = att * seg[HW + p];
}

// out[c][p] = img[c][p] * sa[p]   (float4 over 19.66M elems)
__global__ __launch_bounds__(256) void final_mul_kernel(
    const float* __restrict__ img, const float* __restrict__ sa, float* __restrict__ out) {
  int i = blockIdx.x * blockDim.x + threadIdx.x;  // float4 index, exact 4915200
  int e = i * 4;
  int p = e % HW;  // 76800 % 4 == 0 so float4 stays within one channel row
  float4 v = *(const float4*)(img + e);
  float4 g = *(const float4*)(sa + p);
  float4 o = make_float4(v.x * g.x, v.y * g.y, v.z * g.z, v.w * g.w);
  *(float4*)(out + e) = o;
}

extern "C" void kernel_launch(void* const* d_in, const int* in_sizes, int n_in,
                              void* d_out, int out_size, void* d_ws, size_t ws_size,
                              hipStream_t stream) {
  const float* img = (const float*)d_in[0];
  const float* seg = (const float*)d_in[1];
  int iV0 = 2, iG0 = 3, iV1 = 4, iG1 = 5, iV2 = 6, iG2 = 7;
  if (in_sizes[3] != 2 * NPTS) {  // grouped (reference-arg) order fallback
    iV0 = 2; iV1 = 3; iV2 = 4; iG0 = 5; iG1 = 6; iG2 = 7;
  }
  const float* vf0 = (const float*)d_in[iV0];
  const float* vf1 = (const float*)d_in[iV1];
  const float* vf2 = (const float*)d_in[iV2];
  const int2* g0 = (const int2*)d_in[iG0];
  const int2* g1 = (const int2*)d_in[iG1];
  const int2* g2 = (const int2*)d_in[iG2];
  const float* rw0 = (const float*)d_in[8];
  const float* rb0 = (const float*)d_in[9];
  const float* rw1 = (const float*)d_in[10];
  const float* rb1 = (const float*)d_in[11];
  const float* sbw = (const float*)d_in[12];
  const float* sbb = (const float*)d_in[13];

  char* ws = (char*)d_ws;
  int* w0m = (int*)(ws + 0);
  int* w1m = (int*)(ws + OFF_W1M);
  int* w2m = (int*)(ws + OFF_W2M);
  float* t9 = (float*)(ws + OFF_T9);
  float* Weff0 = (float*)(ws + OFF_WE0);
  float* Weff1 = (float*)(ws + OFF_WE1);
  float* bconst = (float*)(ws + OFF_BC);
  float* sa = (float*)(ws + 0);  // aliases winner maps (dead after t9_kernel)

  float* out = (float*)d_out;

  hipMemsetAsync(w0m, 0xFF, 3 * 307200, stream);  // winners = -1
  prep_and_scatter<<<7 + (NPTS + 255) / 256, 256, 0, stream>>>(
      rw0, rw1, rb0, rb1, sbw, Weff0, Weff1, bconst, g0, g1, g2, w0m, w1m, w2m);
  dim3 tg(HW / 256, NUNIT);
  t9_kernel<<<tg, 256, 0, stream>>>(img, seg, vf0, vf1, vf2, w0m, w1m, w2m,
                                    Weff0, Weff1, sbw, t9);
  conv_sig_kernel<<<HW / 256, 256, 0, stream>>>(t9, bconst, sbb, seg, sa);
  final_mul_kernel<<<(out_size / 4) / 256, 256, 0, stream>>>(img, sa, out);
}